// Round 13
// baseline (365.694 us; speedup 1.0000x reference)
//
#include <hip/hip_runtime.h>

#define NB 4
#define NS 2048
#define ND 512
#define NH 8
#define NDK 64
#define LN_EPS 1e-5f
#define SCLAMP 80.0f

typedef __attribute__((ext_vector_type(8))) short short8;
typedef __attribute__((ext_vector_type(4))) short s16x4;
typedef __attribute__((ext_vector_type(4))) float f32x4;

__device__ inline short f2bf(float x) {
    unsigned u = __builtin_bit_cast(unsigned, x);
    unsigned r = (u + 0x7FFFu + ((u >> 16) & 1u)) >> 16;
    return (short)r;
}
__device__ inline float bf2f(short h) {
    unsigned u = ((unsigned)(unsigned short)h) << 16;
    return __builtin_bit_cast(float, u);
}
// Dekker trunc split, packed return: low 16 = hi part, high 16 = lo part.
__device__ inline unsigned splitT(float x) {
    unsigned u = __builtin_bit_cast(unsigned, x);
    unsigned h = u >> 16;
    float r = x - bf2f((short)h);
    unsigned l = __builtin_bit_cast(unsigned, r) >> 16;
    return (h & 0xFFFFu) | (l << 16);
}

// Swizzled offset (in shorts) within a [rows][64 cols] bf16 LDS tile.
__device__ inline int swzS(int row, int b8) {
    return row * 64 + (((b8) * 8) ^ ((row & 7) << 3));
}
// same, addressed by 8B (4-short) granule g4 (0..15)
__device__ inline int swz4(int row, int g4) {
    return row * 64 + ((((g4 >> 1)) * 8) ^ ((row & 7) << 3)) + (g4 & 1) * 4;
}

// ---------------------------------------------------------------------------
// All three projections in ONE dispatch (blockIdx.z selects Q/K/V).
// P = X @ W^T + b via split-bf16 MFMA (verified round 10 structure).
// z=0,1 (Q,K): bf16 hi+lo out in [B,H,S,DK]. z=2 (V): bf16 V^T [B,H,DK,S].
// ---------------------------------------------------------------------------
__global__ __launch_bounds__(256) void k_projm_all(
    const float* __restrict__ Qx, const float* __restrict__ Kx,
    const float* __restrict__ Vx,
    const float* __restrict__ Wq, const float* __restrict__ bq,
    const float* __restrict__ Wk, const float* __restrict__ bk,
    const float* __restrict__ Wv, const float* __restrict__ bv,
    short* __restrict__ qh, short* __restrict__ ql,
    short* __restrict__ kh, short* __restrict__ kl,
    short* __restrict__ vtb)
{
    __shared__ short WsH[8192], WsL[8192];   // [128 rows][64 k] swizzled
    const int which = blockIdx.z;
    const float* X    = which == 0 ? Qx : (which == 1 ? Kx : Vx);
    const float* W    = which == 0 ? Wq : (which == 1 ? Wk : Wv);
    const float* bias = which == 0 ? bq : (which == 1 ? bk : bv);
    short* outh       = which == 0 ? qh : (which == 1 ? kh : vtb);
    short* outl       = which == 0 ? ql : kl;   // unused when which==2

    const int tid = threadIdx.x;
    const int w = tid >> 6, lane = tid & 63;
    const int lr = lane & 15, lg = lane >> 4;
    const int row0 = blockIdx.y * 64;
    const int col0 = blockIdx.x * 128;
    const int xrow = row0 + w * 16 + lr;

    f32x4 acc[8] = {};

    float4 wb[8], ab[4];
#pragma unroll
    for (int i = 0; i < 8; ++i) {
        int idx = tid + 256 * i, wrow = idx >> 4, g4 = idx & 15;
        wb[i] = *(const float4*)&W[(size_t)(col0 + wrow) * ND + g4 * 4];
    }
#pragma unroll
    for (int ks = 0; ks < 2; ++ks) {
        ab[2*ks+0] = *(const float4*)&X[(size_t)xrow * ND + ks * 32 + lg * 8];
        ab[2*ks+1] = *(const float4*)&X[(size_t)xrow * ND + ks * 32 + lg * 8 + 4];
    }

    for (int kc = 0; kc < 8; ++kc) {
        __syncthreads();
#pragma unroll
        for (int i = 0; i < 8; ++i) {
            int idx = tid + 256 * i, wrow = idx >> 4, g4 = idx & 15;
            s16x4 hv, lv;
            unsigned p0 = splitT(wb[i].x), p1 = splitT(wb[i].y);
            unsigned p2 = splitT(wb[i].z), p3 = splitT(wb[i].w);
            hv[0] = (short)p0; lv[0] = (short)(p0 >> 16);
            hv[1] = (short)p1; lv[1] = (short)(p1 >> 16);
            hv[2] = (short)p2; lv[2] = (short)(p2 >> 16);
            hv[3] = (short)p3; lv[3] = (short)(p3 >> 16);
            int off = swz4(wrow, g4);
            *(s16x4*)&WsH[off] = hv;
            *(s16x4*)&WsL[off] = lv;
        }
        __syncthreads();

        short8 ah[2], al[2];
#pragma unroll
        for (int ks = 0; ks < 2; ++ks) {
#pragma unroll
            for (int j = 0; j < 4; ++j) {
                unsigned p = splitT(ab[2*ks][j]);
                ah[ks][j] = (short)p; al[ks][j] = (short)(p >> 16);
            }
#pragma unroll
            for (int j = 0; j < 4; ++j) {
                unsigned p = splitT(ab[2*ks+1][j]);
                ah[ks][4+j] = (short)p; al[ks][4+j] = (short)(p >> 16);
            }
        }

        if (kc < 7) {
            const int kn = (kc + 1) * 64;
#pragma unroll
            for (int i = 0; i < 8; ++i) {
                int idx = tid + 256 * i, wrow = idx >> 4, g4 = idx & 15;
                wb[i] = *(const float4*)&W[(size_t)(col0 + wrow) * ND + kn + g4 * 4];
            }
#pragma unroll
            for (int ks = 0; ks < 2; ++ks) {
                ab[2*ks+0] = *(const float4*)&X[(size_t)xrow * ND + kn + ks * 32 + lg * 8];
                ab[2*ks+1] = *(const float4*)&X[(size_t)xrow * ND + kn + ks * 32 + lg * 8 + 4];
            }
        }

        __builtin_amdgcn_s_setprio(1);
#pragma unroll
        for (int cs = 0; cs < 8; ++cs)
#pragma unroll
            for (int ks = 0; ks < 2; ++ks) {
                short8 fh = *(const short8*)&WsH[swzS(cs * 16 + lr, ks * 4 + lg)];
                short8 fl = *(const short8*)&WsL[swzS(cs * 16 + lr, ks * 4 + lg)];
                acc[cs] = __builtin_amdgcn_mfma_f32_16x16x32_bf16(ah[ks], fh, acc[cs], 0, 0, 0);
                acc[cs] = __builtin_amdgcn_mfma_f32_16x16x32_bf16(ah[ks], fl, acc[cs], 0, 0, 0);
                acc[cs] = __builtin_amdgcn_mfma_f32_16x16x32_bf16(al[ks], fh, acc[cs], 0, 0, 0);
            }
        __builtin_amdgcn_s_setprio(0);
    }

#pragma unroll
    for (int cs = 0; cs < 8; ++cs) {
        int c = col0 + cs * 16 + lr;
        int h_ = c >> 6, dk = c & (NDK - 1);
        float bv = bias[c];
#pragma unroll
        for (int r = 0; r < 4; ++r) {
            int gr = row0 + w * 16 + lg * 4 + r;
            int b_ = gr >> 11, s_ = gr & (NS - 1);
            float x = acc[cs][r] + bv;
            if (which != 2) {
                size_t idx = (((size_t)b_ * NH + h_) * NS + s_) * NDK + dk;
                short hb = f2bf(x);
                outh[idx] = hb;
                outl[idx] = f2bf(x - bf2f(hb));
            } else {
                size_t idx = (((size_t)b_ * NH + h_) * NDK + dk) * NS + s_;
                outh[idx] = f2bf(x);
            }
        }
    }
}

// ---------------------------------------------------------------------------
// XCD-clustered remap for 512 blocks = 32 bh x 16 rowtiles(128 rows).
// ---------------------------------------------------------------------------
__device__ inline void att_decode2(int wg, int& bh, int& rt) {
    rt = (wg >> 3) & 15;
    bh = (wg & 7) + ((wg >> 7) << 3);
}

// ---------------------------------------------------------------------------
// Fused stats+PV, 32 q-rows per wave (2 row-sets), register-prefetch
// pipeline, setprio around MFMA clusters.  (verified rounds 8-12)
// ---------------------------------------------------------------------------
__global__ __launch_bounds__(256) void k_pvl(
    const short* __restrict__ qh, const short* __restrict__ ql,
    const short* __restrict__ kh, const short* __restrict__ kl,
    const short* __restrict__ vtb,
    float* __restrict__ iLrow, short* __restrict__ ctxb)
{
    __shared__ short KsH[4096], KsL[4096], Vs[4096];
    __shared__ short plbf[4][32][72];
    const int tid = threadIdx.x;
    const int w = tid >> 6, lane = tid & 63;
    const int lr = lane & 15, lg = lane >> 4;
    int bh, rt;
    att_decode2(blockIdx.x, bh, rt);
    const int row0 = rt * 128 + w * 16;    // set0 rows; set1 = +64
    const size_t base = (size_t)bh * NS * NDK;
    const short* vb = vtb + (size_t)bh * NDK * NS;
    const int srow0 = tid >> 3, sb8 = tid & 7;
    const int srow1 = srow0 + 32;

    short8 ah[2][2], al[2][2];
#pragma unroll
    for (int st = 0; st < 2; ++st)
#pragma unroll
        for (int ks = 0; ks < 2; ++ks) {
            size_t idx = base + (size_t)(row0 + st * 64 + lr) * NDK + ks * 32 + lg * 8;
            ah[st][ks] = *(const short8*)&qh[idx];
            al[st][ks] = *(const short8*)&ql[idx];
        }

    float lsum[2][4] = {};
    f32x4 vacc[2][4] = {};

    short8 nh0, nh1, nl0, nl1, nv0, nv1;
    {
        nh0 = *(const short8*)&kh[base + (size_t)(srow0) * NDK + sb8 * 8];
        nh1 = *(const short8*)&kh[base + (size_t)(srow1) * NDK + sb8 * 8];
        nl0 = *(const short8*)&kl[base + (size_t)(srow0) * NDK + sb8 * 8];
        nl1 = *(const short8*)&kl[base + (size_t)(srow1) * NDK + sb8 * 8];
        nv0 = *(const short8*)&vb[(size_t)srow0 * NS + sb8 * 8];
        nv1 = *(const short8*)&vb[(size_t)srow1 * NS + sb8 * 8];
    }

    for (int c = 0; c < 32; ++c) {
        short8 ch0 = nh0, ch1 = nh1, cl0 = nl0, cl1 = nl1, cv0 = nv0, cv1 = nv1;
        __syncthreads();
        *(short8*)&KsH[swzS(srow0, sb8)] = ch0;
        *(short8*)&KsH[swzS(srow1, sb8)] = ch1;
        *(short8*)&KsL[swzS(srow0, sb8)] = cl0;
        *(short8*)&KsL[swzS(srow1, sb8)] = cl1;
        *(short8*)&Vs[swzS(srow0, sb8)] = cv0;
        *(short8*)&Vs[swzS(srow1, sb8)] = cv1;
        __syncthreads();

        if (c < 31) {
            const int coln = (c + 1) * 64;
            nh0 = *(const short8*)&kh[base + (size_t)(coln + srow0) * NDK + sb8 * 8];
            nh1 = *(const short8*)&kh[base + (size_t)(coln + srow1) * NDK + sb8 * 8];
            nl0 = *(const short8*)&kl[base + (size_t)(coln + srow0) * NDK + sb8 * 8];
            nl1 = *(const short8*)&kl[base + (size_t)(coln + srow1) * NDK + sb8 * 8];
            nv0 = *(const short8*)&vb[(size_t)srow0 * NS + coln + sb8 * 8];
            nv1 = *(const short8*)&vb[(size_t)srow1 * NS + coln + sb8 * 8];
        }

        // QK^T: K frag read ONCE, used by both row-sets
        f32x4 sa[2][4] = {};
        __builtin_amdgcn_s_setprio(1);
#pragma unroll
        for (int cs = 0; cs < 4; ++cs)
#pragma unroll
            for (int ks = 0; ks < 2; ++ks) {
                short8 fh = *(const short8*)&KsH[swzS(cs * 16 + lr, ks * 4 + lg)];
                short8 fl = *(const short8*)&KsL[swzS(cs * 16 + lr, ks * 4 + lg)];
#pragma unroll
                for (int st = 0; st < 2; ++st) {
                    sa[st][cs] = __builtin_amdgcn_mfma_f32_16x16x32_bf16(ah[st][ks], fh, sa[st][cs], 0, 0, 0);
                    sa[st][cs] = __builtin_amdgcn_mfma_f32_16x16x32_bf16(ah[st][ks], fl, sa[st][cs], 0, 0, 0);
                    sa[st][cs] = __builtin_amdgcn_mfma_f32_16x16x32_bf16(al[st][ks], fh, sa[st][cs], 0, 0, 0);
                }
            }
        __builtin_amdgcn_s_setprio(0);

#pragma unroll
        for (int st = 0; st < 2; ++st)
#pragma unroll
            for (int cs = 0; cs < 4; ++cs)
#pragma unroll
                for (int r = 0; r < 4; ++r) {
                    float e = __expf(fminf(sa[st][cs][r], SCLAMP));
                    lsum[st][r] += e;
                    plbf[w][st * 16 + lg * 4 + r][cs * 16 + lr] = f2bf(e);
                }

        // PV: V frag read ONCE per (k2,d), used by both row-sets
        __builtin_amdgcn_s_setprio(1);
#pragma unroll
        for (int k2 = 0; k2 < 2; ++k2) {
            short8 pa0 = *(const short8*)&plbf[w][lr][k2 * 32 + lg * 8];
            short8 pa1 = *(const short8*)&plbf[w][16 + lr][k2 * 32 + lg * 8];
#pragma unroll
            for (int d = 0; d < 4; ++d) {
                short8 vf = *(const short8*)&Vs[swzS(d * 16 + lr, k2 * 4 + lg)];
                vacc[0][d] = __builtin_amdgcn_mfma_f32_16x16x32_bf16(pa0, vf, vacc[0][d], 0, 0, 0);
                vacc[1][d] = __builtin_amdgcn_mfma_f32_16x16x32_bf16(pa1, vf, vacc[1][d], 0, 0, 0);
            }
        }
        __builtin_amdgcn_s_setprio(0);
    }

#pragma unroll
    for (int st = 0; st < 2; ++st)
#pragma unroll
        for (int r = 0; r < 4; ++r)
#pragma unroll
            for (int off = 1; off < 16; off <<= 1)
                lsum[st][r] += __shfl_xor(lsum[st][r], off);

    float iL[2][4];
#pragma unroll
    for (int st = 0; st < 2; ++st)
#pragma unroll
        for (int r = 0; r < 4; ++r) iL[st][r] = 1.0f / lsum[st][r];
    if (lr == 0) {
#pragma unroll
        for (int st = 0; st < 2; ++st)
#pragma unroll
            for (int r = 0; r < 4; ++r)
                iLrow[(size_t)bh * NS + row0 + st * 64 + lg * 4 + r] = iL[st][r];
    }
    const int b_ = bh >> 3, h_ = bh & 7;
#pragma unroll
    for (int st = 0; st < 2; ++st)
#pragma unroll
        for (int d = 0; d < 4; ++d)
#pragma unroll
            for (int r = 0; r < 4; ++r) {
                int row = row0 + st * 64 + lg * 4 + r;
                ctxb[((size_t)b_ * NS + row) * ND + h_ * NDK + d * 16 + lr] =
                    f2bf(vacc[st][d][r] * iL[st][r]);
            }
}

// ---------------------------------------------------------------------------
// Attn writer, 32 q-rows per wave, nontemporal p stores (streaming 537 MB
// never re-read -> keep K hi/lo resident in L2), setprio around MFMA.
// ---------------------------------------------------------------------------
__global__ __launch_bounds__(256) void k_attn_write(
    const short* __restrict__ qh, const short* __restrict__ ql,
    const short* __restrict__ kh, const short* __restrict__ kl,
    const float* __restrict__ iLrow, float* __restrict__ attn)
{
    __shared__ short KsH[4096], KsL[4096];
    const int tid = threadIdx.x;
    const int w = tid >> 6, lane = tid & 63;
    const int lr = lane & 15, lg = lane >> 4;
    int bh, rt;
    att_decode2(blockIdx.x, bh, rt);
    const int row0 = rt * 128 + w * 16;
    const size_t base = (size_t)bh * NS * NDK;
    float* ab = attn + (size_t)bh * NS * NS;
    const int srow0 = tid >> 3, sb8 = tid & 7;
    const int srow1 = srow0 + 32;

    short8 ah[2][2], al[2][2];
#pragma unroll
    for (int st = 0; st < 2; ++st)
#pragma unroll
        for (int ks = 0; ks < 2; ++ks) {
            size_t idx = base + (size_t)(row0 + st * 64 + lr) * NDK + ks * 32 + lg * 8;
            ah[st][ks] = *(const short8*)&qh[idx];
            al[st][ks] = *(const short8*)&ql[idx];
        }
    float iLr[2][4];
#pragma unroll
    for (int st = 0; st < 2; ++st)
#pragma unroll
        for (int r = 0; r < 4; ++r)
            iLr[st][r] = iLrow[(size_t)bh * NS + row0 + st * 64 + lg * 4 + r];

    short8 nh0, nh1, nl0, nl1;
    {
        nh0 = *(const short8*)&kh[base + (size_t)(srow0) * NDK + sb8 * 8];
        nh1 = *(const short8*)&kh[base + (size_t)(srow1) * NDK + sb8 * 8];
        nl0 = *(const short8*)&kl[base + (size_t)(srow0) * NDK + sb8 * 8];
        nl1 = *(const short8*)&kl[base + (size_t)(srow1) * NDK + sb8 * 8];
    }

    for (int c = 0; c < 32; ++c) {
        short8 ch0 = nh0, ch1 = nh1, cl0 = nl0, cl1 = nl1;
        __syncthreads();
        *(short8*)&KsH[swzS(srow0, sb8)] = ch0;
        *(short8*)&KsH[swzS(srow1, sb8)] = ch1;
        *(short8*)&KsL[swzS(srow0, sb8)] = cl0;
        *(short8*)&KsL[swzS(srow1, sb8)] = cl1;
        __syncthreads();

        if (c < 31) {
            const int coln = (c + 1) * 64;
            nh0 = *(const short8*)&kh[base + (size_t)(coln + srow0) * NDK + sb8 * 8];
            nh1 = *(const short8*)&kh[base + (size_t)(coln + srow1) * NDK + sb8 * 8];
            nl0 = *(const short8*)&kl[base + (size_t)(coln + srow0) * NDK + sb8 * 8];
            nl1 = *(const short8*)&kl[base + (size_t)(coln + srow1) * NDK + sb8 * 8];
        }

        const int col0 = c * 64;
        f32x4 sa[2][4] = {};
        __builtin_amdgcn_s_setprio(1);
#pragma unroll
        for (int cs = 0; cs < 4; ++cs)
#pragma unroll
            for (int ks = 0; ks < 2; ++ks) {
                short8 fh = *(const short8*)&KsH[swzS(cs * 16 + lr, ks * 4 + lg)];
                short8 fl = *(const short8*)&KsL[swzS(cs * 16 + lr, ks * 4 + lg)];
#pragma unroll
                for (int st = 0; st < 2; ++st) {
                    sa[st][cs] = __builtin_amdgcn_mfma_f32_16x16x32_bf16(ah[st][ks], fh, sa[st][cs], 0, 0, 0);
                    sa[st][cs] = __builtin_amdgcn_mfma_f32_16x16x32_bf16(ah[st][ks], fl, sa[st][cs], 0, 0, 0);
                    sa[st][cs] = __builtin_amdgcn_mfma_f32_16x16x32_bf16(al[st][ks], fh, sa[st][cs], 0, 0, 0);
                }
            }
        __builtin_amdgcn_s_setprio(0);

#pragma unroll
        for (int st = 0; st < 2; ++st)
#pragma unroll
            for (int cs = 0; cs < 4; ++cs)
#pragma unroll
                for (int r = 0; r < 4; ++r) {
                    float p = __expf(fminf(sa[st][cs][r], SCLAMP)) * iLr[st][r];
                    __builtin_nontemporal_store(
                        p, &ab[(size_t)(row0 + st * 64 + lg * 4 + r) * NS + col0 + cs * 16 + lr]);
                }
    }
}

// ---------------------------------------------------------------------------
// Out-projection via MFMA: out = ctx_bf16 @ Wo^T + bo + residual (f32 out).
// ---------------------------------------------------------------------------
__global__ __launch_bounds__(256) void k_outproj_m(
    const short* __restrict__ Xc, const float* __restrict__ W,
    const float* __restrict__ bias, const float* __restrict__ Qin,
    float* __restrict__ out)
{
    __shared__ short WsH[8192], WsL[8192];   // [128 rows][64 k] swizzled
    const int tid = threadIdx.x;
    const int w = tid >> 6, lane = tid & 63;
    const int lr = lane & 15, lg = lane >> 4;
    const int row0 = blockIdx.y * 64;
    const int col0 = blockIdx.x * 128;
    const int xrow = row0 + w * 16 + lr;

    f32x4 acc[8] = {};

    float4 wb[8];
    short8 abn[2];
#pragma unroll
    for (int i = 0; i < 8; ++i) {
        int idx = tid + 256 * i, wrow = idx >> 4, g4 = idx & 15;
        wb[i] = *(const float4*)&W[(size_t)(col0 + wrow) * ND + g4 * 4];
    }
#pragma unroll
    for (int ks = 0; ks < 2; ++ks)
        abn[ks] = *(const short8*)&Xc[(size_t)xrow * ND + ks * 32 + lg * 8];

    for (int kc = 0; kc < 8; ++kc) {
        __syncthreads();
#pragma unroll
        for (int i = 0; i < 8; ++i) {
            int idx = tid + 256 * i, wrow = idx >> 4, g4 = idx & 15;
            s16x4 hv, lv;
            unsigned p0 = splitT(wb[i].x), p1 = splitT(wb[i].y);
            unsigned p2 = splitT(wb[i].z), p3 = splitT(wb[i].w);
            hv[0] = (short)p0; lv[0] = (short)(p0 >> 16);
            hv[1] = (short)p1; lv[1] = (short)(p1 >> 16);
            hv[2] = (short)p2; lv[2] = (short)(p2 >> 16);
            hv[3] = (short)p3; lv[3] = (short)(p3 >> 16);
            int off = swz4(wrow, g4);
            *(s16x4*)&WsH[off] = hv;
            *(s16x4*)&WsL[off] = lv;
        }
        __syncthreads();

        short8 ah[2] = { abn[0], abn[1] };

        if (kc < 7) {
            const int kn = (kc + 1) * 64;
#pragma unroll
            for (int i = 0; i < 8; ++i) {
                int idx = tid + 256 * i, wrow = idx >> 4, g4 = idx & 15;
                wb[i] = *(const float4*)&W[(size_t)(col0 + wrow) * ND + kn + g4 * 4];
            }
#pragma unroll
            for (int ks = 0; ks < 2; ++ks)
                abn[ks] = *(const short8*)&Xc[(size_t)xrow * ND + kn + ks * 32 + lg * 8];
        }

        __builtin_amdgcn_s_setprio(1);
#pragma unroll
        for (int cs = 0; cs < 8; ++cs)
#pragma unroll
            for (int ks = 0; ks < 2; ++ks) {
                short8 fh = *(const short8*)&WsH[swzS(cs * 16 + lr, ks * 4 + lg)];
                short8 fl = *(const short8*)&WsL[swzS(cs * 16 + lr, ks * 4 + lg)];
                acc[cs] = __builtin_amdgcn_mfma_f32_16x16x32_bf16(ah[ks], fh, acc[cs], 0, 0, 0);
                acc[cs] = __builtin_amdgcn_mfma_f32_16x16x32_bf16(ah[ks], fl, acc[cs], 0, 0, 0);
            }
        __builtin_amdgcn_s_setprio(0);
    }

#pragma unroll
    for (int cs = 0; cs < 8; ++cs) {
        int c = col0 + cs * 16 + lr;
        float bv = bias[c];
#pragma unroll
        for (int r = 0; r < 4; ++r) {
            int gr = row0 + w * 16 + lg * 4 + r;
            float res = Qin[(size_t)gr * ND + c];
            out[(size_t)gr * ND + c] = acc[cs][r] + bv + res;
        }
    }
}

// ---------------------------------------------------------------------------
// In-place LayerNorm over last dim (512).
// ---------------------------------------------------------------------------
__global__ __launch_bounds__(256) void k_ln(
    float* __restrict__ out, const float* __restrict__ gamma,
    const float* __restrict__ beta)
{
    const int tid = threadIdx.x;
    float* p = out + (size_t)blockIdx.x * ND;
    float2 v = *(const float2*)&p[tid * 2];

    float s = v.x + v.y;
#pragma unroll
    for (int off = 32; off > 0; off >>= 1) s += __shfl_xor(s, off);
    __shared__ float red1[4];
    __shared__ float red2[4];
    if ((tid & 63) == 0) red1[tid >> 6] = s;
    __syncthreads();
    const float mu = (red1[0] + red1[1] + red1[2] + red1[3]) * (1.0f / ND);

    float dx = v.x - mu, dy = v.y - mu;
    float q = dx * dx + dy * dy;
#pragma unroll
    for (int off = 32; off > 0; off >>= 1) q += __shfl_xor(q, off);
    if ((tid & 63) == 0) red2[tid >> 6] = q;
    __syncthreads();
    const float var = (red2[0] + red2[1] + red2[2] + red2[3]) * (1.0f / ND);
    const float inv = rsqrtf(var + LN_EPS);

    float2 g = *(const float2*)&gamma[tid * 2];
    float2 be = *(const float2*)&beta[tid * 2];
    float2 o = { dx * inv * g.x + be.x, dy * inv * g.y + be.y };
    *(float2*)&p[tid * 2] = o;
}

// ---------------------------------------------------------------------------
extern "C" void kernel_launch(void* const* d_in, const int* in_sizes, int n_in,
                              void* d_out, int out_size, void* d_ws, size_t ws_size,
                              hipStream_t stream)
{
    const float* Q    = (const float*)d_in[0];
    const float* K    = (const float*)d_in[1];
    const float* V    = (const float*)d_in[2];
    const float* Wq   = (const float*)d_in[3];
    const float* bq   = (const float*)d_in[4];
    const float* Wk   = (const float*)d_in[5];
    const float* bk   = (const float*)d_in[6];
    const float* Wv   = (const float*)d_in[7];
    const float* bv   = (const float*)d_in[8];
    const float* Wo   = (const float*)d_in[9];
    const float* bo   = (const float*)d_in[10];
    const float* gam  = (const float*)d_in[11];
    const float* bet  = (const float*)d_in[12];

    float* out  = (float*)d_out;                       // [NB*NS*ND]
    float* attn = out + (size_t)NB * NS * ND;          // [NB*NH*NS*NS]

    const size_t QKV = (size_t)NB * NH * NS * NDK;     // 4.19M elements
    short* qh   = (short*)d_ws;
    short* ql   = qh + QKV;
    short* kh   = ql + QKV;
    short* kl   = kh + QKV;
    short* vtb  = kl + QKV;
    short* ctxb = vtb + QKV;
    float* iLrow = (float*)(ctxb + QKV);               // [32][2048]

    dim3 blk(256);

    dim3 gP(ND / 128, (NB * NS) / 64, 3);              // (4, 128, 3)
    k_projm_all<<<gP, blk, 0, stream>>>(Q, K, V, Wq, bq, Wk, bk, Wv, bv,
                                        qh, ql, kh, kl, vtb);

    dim3 gAtt((NS / 128) * NB * NH);                   // 512, XCD-remapped
    k_pvl<<<gAtt, blk, 0, stream>>>(qh, ql, kh, kl, vtb, iLrow, ctxb);
    k_attn_write<<<gAtt, blk, 0, stream>>>(qh, ql, kh, kl, iLrow, attn);

    dim3 gO(ND / 128, (NB * NS) / 64);                 // (4, 128)
    k_outproj_m<<<gO, blk, 0, stream>>>(ctxb, Wo, bo, Q, out);

    k_ln<<<dim3(NB * NS), blk, 0, stream>>>(out, gam, bet);
}

// Round 14
// 331.042 us; speedup vs baseline: 1.1047x; 1.1047x over previous
//
#include <hip/hip_runtime.h>

#define NB 4
#define NS 2048
#define ND 512
#define NH 8
#define NDK 64
#define LN_EPS 1e-5f
#define SCLAMP 80.0f

typedef __attribute__((ext_vector_type(8))) short short8;
typedef __attribute__((ext_vector_type(4))) short s16x4;
typedef __attribute__((ext_vector_type(4))) float f32x4;

__device__ inline short f2bf(float x) {
    unsigned u = __builtin_bit_cast(unsigned, x);
    unsigned r = (u + 0x7FFFu + ((u >> 16) & 1u)) >> 16;
    return (short)r;
}
__device__ inline float bf2f(short h) {
    unsigned u = ((unsigned)(unsigned short)h) << 16;
    return __builtin_bit_cast(float, u);
}
// Dekker trunc split, packed return: low 16 = hi part, high 16 = lo part.
__device__ inline unsigned splitT(float x) {
    unsigned u = __builtin_bit_cast(unsigned, x);
    unsigned h = u >> 16;
    float r = x - bf2f((short)h);
    unsigned l = __builtin_bit_cast(unsigned, r) >> 16;
    return (h & 0xFFFFu) | (l << 16);
}

// Swizzled offset (in shorts) within a [rows][64 cols] bf16 LDS tile.
__device__ inline int swzS(int row, int b8) {
    return row * 64 + (((b8) * 8) ^ ((row & 7) << 3));
}
// same, addressed by 8B (4-short) granule g4 (0..15)
__device__ inline int swz4(int row, int g4) {
    return row * 64 + ((((g4 >> 1)) * 8) ^ ((row & 7) << 3)) + (g4 & 1) * 4;
}

// ---------------------------------------------------------------------------
// All three projections in ONE dispatch (blockIdx.z selects Q/K/V).
// P = X @ W^T + b via split-bf16 MFMA (verified round 10 structure,
// NO setprio — round-12 loop body verbatim).
// z=0,1 (Q,K): bf16 hi+lo out in [B,H,S,DK]. z=2 (V): bf16 V^T [B,H,DK,S].
// ---------------------------------------------------------------------------
__global__ __launch_bounds__(256) void k_projm_all(
    const float* __restrict__ Qx, const float* __restrict__ Kx,
    const float* __restrict__ Vx,
    const float* __restrict__ Wq, const float* __restrict__ bq,
    const float* __restrict__ Wk, const float* __restrict__ bk,
    const float* __restrict__ Wv, const float* __restrict__ bv,
    short* __restrict__ qh, short* __restrict__ ql,
    short* __restrict__ kh, short* __restrict__ kl,
    short* __restrict__ vtb)
{
    __shared__ short WsH[8192], WsL[8192];   // [128 rows][64 k] swizzled
    const int which = blockIdx.z;
    const float* X    = which == 0 ? Qx : (which == 1 ? Kx : Vx);
    const float* W    = which == 0 ? Wq : (which == 1 ? Wk : Wv);
    const float* bias = which == 0 ? bq : (which == 1 ? bk : bv);
    short* outh       = which == 0 ? qh : (which == 1 ? kh : vtb);
    short* outl       = which == 0 ? ql : kl;   // unused when which==2

    const int tid = threadIdx.x;
    const int w = tid >> 6, lane = tid & 63;
    const int lr = lane & 15, lg = lane >> 4;
    const int row0 = blockIdx.y * 64;
    const int col0 = blockIdx.x * 128;
    const int xrow = row0 + w * 16 + lr;

    f32x4 acc[8] = {};

    float4 wb[8], ab[4];
#pragma unroll
    for (int i = 0; i < 8; ++i) {
        int idx = tid + 256 * i, wrow = idx >> 4, g4 = idx & 15;
        wb[i] = *(const float4*)&W[(size_t)(col0 + wrow) * ND + g4 * 4];
    }
#pragma unroll
    for (int ks = 0; ks < 2; ++ks) {
        ab[2*ks+0] = *(const float4*)&X[(size_t)xrow * ND + ks * 32 + lg * 8];
        ab[2*ks+1] = *(const float4*)&X[(size_t)xrow * ND + ks * 32 + lg * 8 + 4];
    }

    for (int kc = 0; kc < 8; ++kc) {
        __syncthreads();
#pragma unroll
        for (int i = 0; i < 8; ++i) {
            int idx = tid + 256 * i, wrow = idx >> 4, g4 = idx & 15;
            s16x4 hv, lv;
            unsigned p0 = splitT(wb[i].x), p1 = splitT(wb[i].y);
            unsigned p2 = splitT(wb[i].z), p3 = splitT(wb[i].w);
            hv[0] = (short)p0; lv[0] = (short)(p0 >> 16);
            hv[1] = (short)p1; lv[1] = (short)(p1 >> 16);
            hv[2] = (short)p2; lv[2] = (short)(p2 >> 16);
            hv[3] = (short)p3; lv[3] = (short)(p3 >> 16);
            int off = swz4(wrow, g4);
            *(s16x4*)&WsH[off] = hv;
            *(s16x4*)&WsL[off] = lv;
        }
        __syncthreads();

        short8 ah[2], al[2];
#pragma unroll
        for (int ks = 0; ks < 2; ++ks) {
#pragma unroll
            for (int j = 0; j < 4; ++j) {
                unsigned p = splitT(ab[2*ks][j]);
                ah[ks][j] = (short)p; al[ks][j] = (short)(p >> 16);
            }
#pragma unroll
            for (int j = 0; j < 4; ++j) {
                unsigned p = splitT(ab[2*ks+1][j]);
                ah[ks][4+j] = (short)p; al[ks][4+j] = (short)(p >> 16);
            }
        }

        if (kc < 7) {
            const int kn = (kc + 1) * 64;
#pragma unroll
            for (int i = 0; i < 8; ++i) {
                int idx = tid + 256 * i, wrow = idx >> 4, g4 = idx & 15;
                wb[i] = *(const float4*)&W[(size_t)(col0 + wrow) * ND + kn + g4 * 4];
            }
#pragma unroll
            for (int ks = 0; ks < 2; ++ks) {
                ab[2*ks+0] = *(const float4*)&X[(size_t)xrow * ND + kn + ks * 32 + lg * 8];
                ab[2*ks+1] = *(const float4*)&X[(size_t)xrow * ND + kn + ks * 32 + lg * 8 + 4];
            }
        }

#pragma unroll
        for (int cs = 0; cs < 8; ++cs)
#pragma unroll
            for (int ks = 0; ks < 2; ++ks) {
                short8 fh = *(const short8*)&WsH[swzS(cs * 16 + lr, ks * 4 + lg)];
                short8 fl = *(const short8*)&WsL[swzS(cs * 16 + lr, ks * 4 + lg)];
                acc[cs] = __builtin_amdgcn_mfma_f32_16x16x32_bf16(ah[ks], fh, acc[cs], 0, 0, 0);
                acc[cs] = __builtin_amdgcn_mfma_f32_16x16x32_bf16(ah[ks], fl, acc[cs], 0, 0, 0);
                acc[cs] = __builtin_amdgcn_mfma_f32_16x16x32_bf16(al[ks], fh, acc[cs], 0, 0, 0);
            }
    }

#pragma unroll
    for (int cs = 0; cs < 8; ++cs) {
        int c = col0 + cs * 16 + lr;
        int h_ = c >> 6, dk = c & (NDK - 1);
        float bv = bias[c];
#pragma unroll
        for (int r = 0; r < 4; ++r) {
            int gr = row0 + w * 16 + lg * 4 + r;
            int b_ = gr >> 11, s_ = gr & (NS - 1);
            float x = acc[cs][r] + bv;
            if (which != 2) {
                size_t idx = (((size_t)b_ * NH + h_) * NS + s_) * NDK + dk;
                short hb = f2bf(x);
                outh[idx] = hb;
                outl[idx] = f2bf(x - bf2f(hb));
            } else {
                size_t idx = (((size_t)b_ * NH + h_) * NDK + dk) * NS + s_;
                outh[idx] = f2bf(x);
            }
        }
    }
}

// ---------------------------------------------------------------------------
// XCD-clustered remap for 512 blocks = 32 bh x 16 rowtiles(128 rows).
// ---------------------------------------------------------------------------
__device__ inline void att_decode2(int wg, int& bh, int& rt) {
    rt = (wg >> 3) & 15;
    bh = (wg & 7) + ((wg >> 7) << 3);
}

// ---------------------------------------------------------------------------
// Fused stats+PV, 32 q-rows per wave (2 row-sets), register-prefetch
// pipeline.  (round-12 body verbatim — no setprio)
// ---------------------------------------------------------------------------
__global__ __launch_bounds__(256) void k_pvl(
    const short* __restrict__ qh, const short* __restrict__ ql,
    const short* __restrict__ kh, const short* __restrict__ kl,
    const short* __restrict__ vtb,
    float* __restrict__ iLrow, short* __restrict__ ctxb)
{
    __shared__ short KsH[4096], KsL[4096], Vs[4096];
    __shared__ short plbf[4][32][72];
    const int tid = threadIdx.x;
    const int w = tid >> 6, lane = tid & 63;
    const int lr = lane & 15, lg = lane >> 4;
    int bh, rt;
    att_decode2(blockIdx.x, bh, rt);
    const int row0 = rt * 128 + w * 16;    // set0 rows; set1 = +64
    const size_t base = (size_t)bh * NS * NDK;
    const short* vb = vtb + (size_t)bh * NDK * NS;
    const int srow0 = tid >> 3, sb8 = tid & 7;
    const int srow1 = srow0 + 32;

    short8 ah[2][2], al[2][2];
#pragma unroll
    for (int st = 0; st < 2; ++st)
#pragma unroll
        for (int ks = 0; ks < 2; ++ks) {
            size_t idx = base + (size_t)(row0 + st * 64 + lr) * NDK + ks * 32 + lg * 8;
            ah[st][ks] = *(const short8*)&qh[idx];
            al[st][ks] = *(const short8*)&ql[idx];
        }

    float lsum[2][4] = {};
    f32x4 vacc[2][4] = {};

    short8 nh0, nh1, nl0, nl1, nv0, nv1;
    {
        nh0 = *(const short8*)&kh[base + (size_t)(srow0) * NDK + sb8 * 8];
        nh1 = *(const short8*)&kh[base + (size_t)(srow1) * NDK + sb8 * 8];
        nl0 = *(const short8*)&kl[base + (size_t)(srow0) * NDK + sb8 * 8];
        nl1 = *(const short8*)&kl[base + (size_t)(srow1) * NDK + sb8 * 8];
        nv0 = *(const short8*)&vb[(size_t)srow0 * NS + sb8 * 8];
        nv1 = *(const short8*)&vb[(size_t)srow1 * NS + sb8 * 8];
    }

    for (int c = 0; c < 32; ++c) {
        short8 ch0 = nh0, ch1 = nh1, cl0 = nl0, cl1 = nl1, cv0 = nv0, cv1 = nv1;
        __syncthreads();
        *(short8*)&KsH[swzS(srow0, sb8)] = ch0;
        *(short8*)&KsH[swzS(srow1, sb8)] = ch1;
        *(short8*)&KsL[swzS(srow0, sb8)] = cl0;
        *(short8*)&KsL[swzS(srow1, sb8)] = cl1;
        *(short8*)&Vs[swzS(srow0, sb8)] = cv0;
        *(short8*)&Vs[swzS(srow1, sb8)] = cv1;
        __syncthreads();

        if (c < 31) {
            const int coln = (c + 1) * 64;
            nh0 = *(const short8*)&kh[base + (size_t)(coln + srow0) * NDK + sb8 * 8];
            nh1 = *(const short8*)&kh[base + (size_t)(coln + srow1) * NDK + sb8 * 8];
            nl0 = *(const short8*)&kl[base + (size_t)(coln + srow0) * NDK + sb8 * 8];
            nl1 = *(const short8*)&kl[base + (size_t)(coln + srow1) * NDK + sb8 * 8];
            nv0 = *(const short8*)&vb[(size_t)srow0 * NS + coln + sb8 * 8];
            nv1 = *(const short8*)&vb[(size_t)srow1 * NS + coln + sb8 * 8];
        }

        // QK^T: K frag read ONCE, used by both row-sets
        f32x4 sa[2][4] = {};
#pragma unroll
        for (int cs = 0; cs < 4; ++cs)
#pragma unroll
            for (int ks = 0; ks < 2; ++ks) {
                short8 fh = *(const short8*)&KsH[swzS(cs * 16 + lr, ks * 4 + lg)];
                short8 fl = *(const short8*)&KsL[swzS(cs * 16 + lr, ks * 4 + lg)];
#pragma unroll
                for (int st = 0; st < 2; ++st) {
                    sa[st][cs] = __builtin_amdgcn_mfma_f32_16x16x32_bf16(ah[st][ks], fh, sa[st][cs], 0, 0, 0);
                    sa[st][cs] = __builtin_amdgcn_mfma_f32_16x16x32_bf16(ah[st][ks], fl, sa[st][cs], 0, 0, 0);
                    sa[st][cs] = __builtin_amdgcn_mfma_f32_16x16x32_bf16(al[st][ks], fh, sa[st][cs], 0, 0, 0);
                }
            }

#pragma unroll
        for (int st = 0; st < 2; ++st)
#pragma unroll
            for (int cs = 0; cs < 4; ++cs)
#pragma unroll
                for (int r = 0; r < 4; ++r) {
                    float e = __expf(fminf(sa[st][cs][r], SCLAMP));
                    lsum[st][r] += e;
                    plbf[w][st * 16 + lg * 4 + r][cs * 16 + lr] = f2bf(e);
                }

        // PV: V frag read ONCE per (k2,d), used by both row-sets
#pragma unroll
        for (int k2 = 0; k2 < 2; ++k2) {
            short8 pa0 = *(const short8*)&plbf[w][lr][k2 * 32 + lg * 8];
            short8 pa1 = *(const short8*)&plbf[w][16 + lr][k2 * 32 + lg * 8];
#pragma unroll
            for (int d = 0; d < 4; ++d) {
                short8 vf = *(const short8*)&Vs[swzS(d * 16 + lr, k2 * 4 + lg)];
                vacc[0][d] = __builtin_amdgcn_mfma_f32_16x16x32_bf16(pa0, vf, vacc[0][d], 0, 0, 0);
                vacc[1][d] = __builtin_amdgcn_mfma_f32_16x16x32_bf16(pa1, vf, vacc[1][d], 0, 0, 0);
            }
        }
    }

#pragma unroll
    for (int st = 0; st < 2; ++st)
#pragma unroll
        for (int r = 0; r < 4; ++r)
#pragma unroll
            for (int off = 1; off < 16; off <<= 1)
                lsum[st][r] += __shfl_xor(lsum[st][r], off);

    float iL[2][4];
#pragma unroll
    for (int st = 0; st < 2; ++st)
#pragma unroll
        for (int r = 0; r < 4; ++r) iL[st][r] = 1.0f / lsum[st][r];
    if (lr == 0) {
#pragma unroll
        for (int st = 0; st < 2; ++st)
#pragma unroll
            for (int r = 0; r < 4; ++r)
                iLrow[(size_t)bh * NS + row0 + st * 64 + lg * 4 + r] = iL[st][r];
    }
    const int b_ = bh >> 3, h_ = bh & 7;
#pragma unroll
    for (int st = 0; st < 2; ++st)
#pragma unroll
        for (int d = 0; d < 4; ++d)
#pragma unroll
            for (int r = 0; r < 4; ++r) {
                int row = row0 + st * 64 + lg * 4 + r;
                ctxb[((size_t)b_ * NS + row) * ND + h_ * NDK + d * 16 + lr] =
                    f2bf(vacc[st][d][r] * iL[st][r]);
            }
}

// ---------------------------------------------------------------------------
// Attn writer, 32 q-rows per wave.  (round-12 body verbatim — normal stores)
// ---------------------------------------------------------------------------
__global__ __launch_bounds__(256) void k_attn_write(
    const short* __restrict__ qh, const short* __restrict__ ql,
    const short* __restrict__ kh, const short* __restrict__ kl,
    const float* __restrict__ iLrow, float* __restrict__ attn)
{
    __shared__ short KsH[4096], KsL[4096];
    const int tid = threadIdx.x;
    const int w = tid >> 6, lane = tid & 63;
    const int lr = lane & 15, lg = lane >> 4;
    int bh, rt;
    att_decode2(blockIdx.x, bh, rt);
    const int row0 = rt * 128 + w * 16;
    const size_t base = (size_t)bh * NS * NDK;
    float* ab = attn + (size_t)bh * NS * NS;
    const int srow0 = tid >> 3, sb8 = tid & 7;
    const int srow1 = srow0 + 32;

    short8 ah[2][2], al[2][2];
#pragma unroll
    for (int st = 0; st < 2; ++st)
#pragma unroll
        for (int ks = 0; ks < 2; ++ks) {
            size_t idx = base + (size_t)(row0 + st * 64 + lr) * NDK + ks * 32 + lg * 8;
            ah[st][ks] = *(const short8*)&qh[idx];
            al[st][ks] = *(const short8*)&ql[idx];
        }
    float iLr[2][4];
#pragma unroll
    for (int st = 0; st < 2; ++st)
#pragma unroll
        for (int r = 0; r < 4; ++r)
            iLr[st][r] = iLrow[(size_t)bh * NS + row0 + st * 64 + lg * 4 + r];

    short8 nh0, nh1, nl0, nl1;
    {
        nh0 = *(const short8*)&kh[base + (size_t)(srow0) * NDK + sb8 * 8];
        nh1 = *(const short8*)&kh[base + (size_t)(srow1) * NDK + sb8 * 8];
        nl0 = *(const short8*)&kl[base + (size_t)(srow0) * NDK + sb8 * 8];
        nl1 = *(const short8*)&kl[base + (size_t)(srow1) * NDK + sb8 * 8];
    }

    for (int c = 0; c < 32; ++c) {
        short8 ch0 = nh0, ch1 = nh1, cl0 = nl0, cl1 = nl1;
        __syncthreads();
        *(short8*)&KsH[swzS(srow0, sb8)] = ch0;
        *(short8*)&KsH[swzS(srow1, sb8)] = ch1;
        *(short8*)&KsL[swzS(srow0, sb8)] = cl0;
        *(short8*)&KsL[swzS(srow1, sb8)] = cl1;
        __syncthreads();

        if (c < 31) {
            const int coln = (c + 1) * 64;
            nh0 = *(const short8*)&kh[base + (size_t)(coln + srow0) * NDK + sb8 * 8];
            nh1 = *(const short8*)&kh[base + (size_t)(coln + srow1) * NDK + sb8 * 8];
            nl0 = *(const short8*)&kl[base + (size_t)(coln + srow0) * NDK + sb8 * 8];
            nl1 = *(const short8*)&kl[base + (size_t)(coln + srow1) * NDK + sb8 * 8];
        }

        const int col0 = c * 64;
        f32x4 sa[2][4] = {};
#pragma unroll
        for (int cs = 0; cs < 4; ++cs)
#pragma unroll
            for (int ks = 0; ks < 2; ++ks) {
                short8 fh = *(const short8*)&KsH[swzS(cs * 16 + lr, ks * 4 + lg)];
                short8 fl = *(const short8*)&KsL[swzS(cs * 16 + lr, ks * 4 + lg)];
#pragma unroll
                for (int st = 0; st < 2; ++st) {
                    sa[st][cs] = __builtin_amdgcn_mfma_f32_16x16x32_bf16(ah[st][ks], fh, sa[st][cs], 0, 0, 0);
                    sa[st][cs] = __builtin_amdgcn_mfma_f32_16x16x32_bf16(ah[st][ks], fl, sa[st][cs], 0, 0, 0);
                    sa[st][cs] = __builtin_amdgcn_mfma_f32_16x16x32_bf16(al[st][ks], fh, sa[st][cs], 0, 0, 0);
                }
            }

#pragma unroll
        for (int st = 0; st < 2; ++st)
#pragma unroll
            for (int cs = 0; cs < 4; ++cs)
#pragma unroll
                for (int r = 0; r < 4; ++r) {
                    float p = __expf(fminf(sa[st][cs][r], SCLAMP)) * iLr[st][r];
                    ab[(size_t)(row0 + st * 64 + lg * 4 + r) * NS + col0 + cs * 16 + lr] = p;
                }
    }
}

// ---------------------------------------------------------------------------
// Out-projection via MFMA.  (round-12 body verbatim — no setprio)
// ---------------------------------------------------------------------------
__global__ __launch_bounds__(256) void k_outproj_m(
    const short* __restrict__ Xc, const float* __restrict__ W,
    const float* __restrict__ bias, const float* __restrict__ Qin,
    float* __restrict__ out)
{
    __shared__ short WsH[8192], WsL[8192];   // [128 rows][64 k] swizzled
    const int tid = threadIdx.x;
    const int w = tid >> 6, lane = tid & 63;
    const int lr = lane & 15, lg = lane >> 4;
    const int row0 = blockIdx.y * 64;
    const int col0 = blockIdx.x * 128;
    const int xrow = row0 + w * 16 + lr;

    f32x4 acc[8] = {};

    float4 wb[8];
    short8 abn[2];
#pragma unroll
    for (int i = 0; i < 8; ++i) {
        int idx = tid + 256 * i, wrow = idx >> 4, g4 = idx & 15;
        wb[i] = *(const float4*)&W[(size_t)(col0 + wrow) * ND + g4 * 4];
    }
#pragma unroll
    for (int ks = 0; ks < 2; ++ks)
        abn[ks] = *(const short8*)&Xc[(size_t)xrow * ND + ks * 32 + lg * 8];

    for (int kc = 0; kc < 8; ++kc) {
        __syncthreads();
#pragma unroll
        for (int i = 0; i < 8; ++i) {
            int idx = tid + 256 * i, wrow = idx >> 4, g4 = idx & 15;
            s16x4 hv, lv;
            unsigned p0 = splitT(wb[i].x), p1 = splitT(wb[i].y);
            unsigned p2 = splitT(wb[i].z), p3 = splitT(wb[i].w);
            hv[0] = (short)p0; lv[0] = (short)(p0 >> 16);
            hv[1] = (short)p1; lv[1] = (short)(p1 >> 16);
            hv[2] = (short)p2; lv[2] = (short)(p2 >> 16);
            hv[3] = (short)p3; lv[3] = (short)(p3 >> 16);
            int off = swz4(wrow, g4);
            *(s16x4*)&WsH[off] = hv;
            *(s16x4*)&WsL[off] = lv;
        }
        __syncthreads();

        short8 ah[2] = { abn[0], abn[1] };

        if (kc < 7) {
            const int kn = (kc + 1) * 64;
#pragma unroll
            for (int i = 0; i < 8; ++i) {
                int idx = tid + 256 * i, wrow = idx >> 4, g4 = idx & 15;
                wb[i] = *(const float4*)&W[(size_t)(col0 + wrow) * ND + kn + g4 * 4];
            }
#pragma unroll
            for (int ks = 0; ks < 2; ++ks)
                abn[ks] = *(const short8*)&Xc[(size_t)xrow * ND + kn + ks * 32 + lg * 8];
        }

#pragma unroll
        for (int cs = 0; cs < 8; ++cs)
#pragma unroll
            for (int ks = 0; ks < 2; ++ks) {
                short8 fh = *(const short8*)&WsH[swzS(cs * 16 + lr, ks * 4 + lg)];
                short8 fl = *(const short8*)&WsL[swzS(cs * 16 + lr, ks * 4 + lg)];
                acc[cs] = __builtin_amdgcn_mfma_f32_16x16x32_bf16(ah[ks], fh, acc[cs], 0, 0, 0);
                acc[cs] = __builtin_amdgcn_mfma_f32_16x16x32_bf16(ah[ks], fl, acc[cs], 0, 0, 0);
            }
    }

#pragma unroll
    for (int cs = 0; cs < 8; ++cs) {
        int c = col0 + cs * 16 + lr;
        float bv = bias[c];
#pragma unroll
        for (int r = 0; r < 4; ++r) {
            int gr = row0 + w * 16 + lg * 4 + r;
            float res = Qin[(size_t)gr * ND + c];
            out[(size_t)gr * ND + c] = acc[cs][r] + bv + res;
        }
    }
}

// ---------------------------------------------------------------------------
// In-place LayerNorm over last dim (512).
// ---------------------------------------------------------------------------
__global__ __launch_bounds__(256) void k_ln(
    float* __restrict__ out, const float* __restrict__ gamma,
    const float* __restrict__ beta)
{
    const int tid = threadIdx.x;
    float* p = out + (size_t)blockIdx.x * ND;
    float2 v = *(const float2*)&p[tid * 2];

    float s = v.x + v.y;
#pragma unroll
    for (int off = 32; off > 0; off >>= 1) s += __shfl_xor(s, off);
    __shared__ float red1[4];
    __shared__ float red2[4];
    if ((tid & 63) == 0) red1[tid >> 6] = s;
    __syncthreads();
    const float mu = (red1[0] + red1[1] + red1[2] + red1[3]) * (1.0f / ND);

    float dx = v.x - mu, dy = v.y - mu;
    float q = dx * dx + dy * dy;
#pragma unroll
    for (int off = 32; off > 0; off >>= 1) q += __shfl_xor(q, off);
    if ((tid & 63) == 0) red2[tid >> 6] = q;
    __syncthreads();
    const float var = (red2[0] + red2[1] + red2[2] + red2[3]) * (1.0f / ND);
    const float inv = rsqrtf(var + LN_EPS);

    float2 g = *(const float2*)&gamma[tid * 2];
    float2 be = *(const float2*)&beta[tid * 2];
    float2 o = { dx * inv * g.x + be.x, dy * inv * g.y + be.y };
    *(float2*)&p[tid * 2] = o;
}

// ---------------------------------------------------------------------------
extern "C" void kernel_launch(void* const* d_in, const int* in_sizes, int n_in,
                              void* d_out, int out_size, void* d_ws, size_t ws_size,
                              hipStream_t stream)
{
    const float* Q    = (const float*)d_in[0];
    const float* K    = (const float*)d_in[1];
    const float* V    = (const float*)d_in[2];
    const float* Wq   = (const float*)d_in[3];
    const float* bq   = (const float*)d_in[4];
    const float* Wk   = (const float*)d_in[5];
    const float* bk   = (const float*)d_in[6];
    const float* Wv   = (const float*)d_in[7];
    const float* bv   = (const float*)d_in[8];
    const float* Wo   = (const float*)d_in[9];
    const float* bo   = (const float*)d_in[10];
    const float* gam  = (const float*)d_in[11];
    const float* bet  = (const float*)d_in[12];

    float* out  = (float*)d_out;                       // [NB*NS*ND]
    float* attn = out + (size_t)NB * NS * ND;          // [NB*NH*NS*NS]

    const size_t QKV = (size_t)NB * NH * NS * NDK;     // 4.19M elements
    short* qh   = (short*)d_ws;
    short* ql   = qh + QKV;
    short* kh   = ql + QKV;
    short* kl   = kh + QKV;
    short* vtb  = kl + QKV;
    short* ctxb = vtb + QKV;
    float* iLrow = (float*)(ctxb + QKV);               // [32][2048]

    dim3 blk(256);

    dim3 gP(ND / 128, (NB * NS) / 64, 3);              // (4, 128, 3)
    k_projm_all<<<gP, blk, 0, stream>>>(Q, K, V, Wq, bq, Wk, bk, Wv, bv,
                                        qh, ql, kh, kl, vtb);

    dim3 gAtt((NS / 128) * NB * NH);                   // 512, XCD-remapped
    k_pvl<<<gAtt, blk, 0, stream>>>(qh, ql, kh, kl, vtb, iLrow, ctxb);
    k_attn_write<<<gAtt, blk, 0, stream>>>(qh, ql, kh, kl, iLrow, attn);

    dim3 gO(ND / 128, (NB * NS) / 64);                 // (4, 128)
    k_outproj_m<<<gO, blk, 0, stream>>>(ctxb, Wo, bo, Q, out);

    k_ln<<<dim3(NB * NS), blk, 0, stream>>>(out, gam, bet);
}

// Round 15
// 304.576 us; speedup vs baseline: 1.2007x; 1.0869x over previous
//
#include <hip/hip_runtime.h>

#define NB 4
#define NS 2048
#define ND 512
#define NH 8
#define NDK 64
#define LN_EPS 1e-5f
#define SCLAMP 115.0f   // clamp in log2 domain (scores*log2e ~<75 << 115)
#define LOG2E 1.44269504f

typedef __attribute__((ext_vector_type(8))) short short8;
typedef __attribute__((ext_vector_type(4))) short s16x4;
typedef __attribute__((ext_vector_type(4))) float f32x4;

__device__ inline short f2bf(float x) {
    unsigned u = __builtin_bit_cast(unsigned, x);
    unsigned r = (u + 0x7FFFu + ((u >> 16) & 1u)) >> 16;
    return (short)r;
}
__device__ inline float bf2f(short h) {
    unsigned u = ((unsigned)(unsigned short)h) << 16;
    return __builtin_bit_cast(float, u);
}
// Dekker trunc split, packed return: low 16 = hi part, high 16 = lo part.
__device__ inline unsigned splitT(float x) {
    unsigned u = __builtin_bit_cast(unsigned, x);
    unsigned h = u >> 16;
    float r = x - bf2f((short)h);
    unsigned l = __builtin_bit_cast(unsigned, r) >> 16;
    return (h & 0xFFFFu) | (l << 16);
}

// Swizzled offset (in shorts) within a [rows][64 cols] bf16 LDS tile.
__device__ inline int swzS(int row, int b8) {
    return row * 64 + (((b8) * 8) ^ ((row & 7) << 3));
}
// same, addressed by 8B (4-short) granule g4 (0..15)
__device__ inline int swz4(int row, int g4) {
    return row * 64 + ((((g4 >> 1)) * 8) ^ ((row & 7) << 3)) + (g4 & 1) * 4;
}

// ---------------------------------------------------------------------------
// All three projections in ONE dispatch (blockIdx.z selects Q/K/V).
// P = X @ W^T + b via split-bf16 MFMA. Q output is PRE-SCALED by log2(e)
// so the attention exp becomes a bare v_exp_f32 (exp2).
// z=0,1 (Q,K): bf16 hi+lo out in [B,H,S,DK]. z=2 (V): bf16 V^T [B,H,DK,S].
// ---------------------------------------------------------------------------
__global__ __launch_bounds__(256) void k_projm_all(
    const float* __restrict__ Qx, const float* __restrict__ Kx,
    const float* __restrict__ Vx,
    const float* __restrict__ Wq, const float* __restrict__ bq,
    const float* __restrict__ Wk, const float* __restrict__ bk,
    const float* __restrict__ Wv, const float* __restrict__ bv,
    short* __restrict__ qh, short* __restrict__ ql,
    short* __restrict__ kh, short* __restrict__ kl,
    short* __restrict__ vtb)
{
    __shared__ short WsH[8192], WsL[8192];   // [128 rows][64 k] swizzled
    const int which = blockIdx.z;
    const float* X    = which == 0 ? Qx : (which == 1 ? Kx : Vx);
    const float* W    = which == 0 ? Wq : (which == 1 ? Wk : Wv);
    const float* bias = which == 0 ? bq : (which == 1 ? bk : bv);
    short* outh       = which == 0 ? qh : (which == 1 ? kh : vtb);
    short* outl       = which == 0 ? ql : kl;   // unused when which==2

    const int tid = threadIdx.x;
    const int w = tid >> 6, lane = tid & 63;
    const int lr = lane & 15, lg = lane >> 4;
    const int row0 = blockIdx.y * 64;
    const int col0 = blockIdx.x * 128;
    const int xrow = row0 + w * 16 + lr;

    f32x4 acc[8] = {};

    float4 wb[8], ab[4];
#pragma unroll
    for (int i = 0; i < 8; ++i) {
        int idx = tid + 256 * i, wrow = idx >> 4, g4 = idx & 15;
        wb[i] = *(const float4*)&W[(size_t)(col0 + wrow) * ND + g4 * 4];
    }
#pragma unroll
    for (int ks = 0; ks < 2; ++ks) {
        ab[2*ks+0] = *(const float4*)&X[(size_t)xrow * ND + ks * 32 + lg * 8];
        ab[2*ks+1] = *(const float4*)&X[(size_t)xrow * ND + ks * 32 + lg * 8 + 4];
    }

    for (int kc = 0; kc < 8; ++kc) {
        __syncthreads();
#pragma unroll
        for (int i = 0; i < 8; ++i) {
            int idx = tid + 256 * i, wrow = idx >> 4, g4 = idx & 15;
            s16x4 hv, lv;
            unsigned p0 = splitT(wb[i].x), p1 = splitT(wb[i].y);
            unsigned p2 = splitT(wb[i].z), p3 = splitT(wb[i].w);
            hv[0] = (short)p0; lv[0] = (short)(p0 >> 16);
            hv[1] = (short)p1; lv[1] = (short)(p1 >> 16);
            hv[2] = (short)p2; lv[2] = (short)(p2 >> 16);
            hv[3] = (short)p3; lv[3] = (short)(p3 >> 16);
            int off = swz4(wrow, g4);
            *(s16x4*)&WsH[off] = hv;
            *(s16x4*)&WsL[off] = lv;
        }
        __syncthreads();

        short8 ah[2], al[2];
#pragma unroll
        for (int ks = 0; ks < 2; ++ks) {
#pragma unroll
            for (int j = 0; j < 4; ++j) {
                unsigned p = splitT(ab[2*ks][j]);
                ah[ks][j] = (short)p; al[ks][j] = (short)(p >> 16);
            }
#pragma unroll
            for (int j = 0; j < 4; ++j) {
                unsigned p = splitT(ab[2*ks+1][j]);
                ah[ks][4+j] = (short)p; al[ks][4+j] = (short)(p >> 16);
            }
        }

        if (kc < 7) {
            const int kn = (kc + 1) * 64;
#pragma unroll
            for (int i = 0; i < 8; ++i) {
                int idx = tid + 256 * i, wrow = idx >> 4, g4 = idx & 15;
                wb[i] = *(const float4*)&W[(size_t)(col0 + wrow) * ND + kn + g4 * 4];
            }
#pragma unroll
            for (int ks = 0; ks < 2; ++ks) {
                ab[2*ks+0] = *(const float4*)&X[(size_t)xrow * ND + kn + ks * 32 + lg * 8];
                ab[2*ks+1] = *(const float4*)&X[(size_t)xrow * ND + kn + ks * 32 + lg * 8 + 4];
            }
        }

#pragma unroll
        for (int cs = 0; cs < 8; ++cs)
#pragma unroll
            for (int ks = 0; ks < 2; ++ks) {
                short8 fh = *(const short8*)&WsH[swzS(cs * 16 + lr, ks * 4 + lg)];
                short8 fl = *(const short8*)&WsL[swzS(cs * 16 + lr, ks * 4 + lg)];
                acc[cs] = __builtin_amdgcn_mfma_f32_16x16x32_bf16(ah[ks], fh, acc[cs], 0, 0, 0);
                acc[cs] = __builtin_amdgcn_mfma_f32_16x16x32_bf16(ah[ks], fl, acc[cs], 0, 0, 0);
                acc[cs] = __builtin_amdgcn_mfma_f32_16x16x32_bf16(al[ks], fh, acc[cs], 0, 0, 0);
            }
    }

#pragma unroll
    for (int cs = 0; cs < 8; ++cs) {
        int c = col0 + cs * 16 + lr;
        int h_ = c >> 6, dk = c & (NDK - 1);
        float bv = bias[c];
#pragma unroll
        for (int r = 0; r < 4; ++r) {
            int gr = row0 + w * 16 + lg * 4 + r;
            int b_ = gr >> 11, s_ = gr & (NS - 1);
            float x = acc[cs][r] + bv;
            if (which == 0) x *= LOG2E;      // fold ln2 into Q: exp(s)=exp2(s')
            if (which != 2) {
                size_t idx = (((size_t)b_ * NH + h_) * NS + s_) * NDK + dk;
                short hb = f2bf(x);
                outh[idx] = hb;
                outl[idx] = f2bf(x - bf2f(hb));
            } else {
                size_t idx = (((size_t)b_ * NH + h_) * NDK + dk) * NS + s_;
                outh[idx] = f2bf(x);
            }
        }
    }
}

// ---------------------------------------------------------------------------
// XCD-clustered remap for 512 blocks = 32 bh x 16 rowtiles(128 rows).
// ---------------------------------------------------------------------------
__device__ inline void att_decode2(int wg, int& bh, int& rt) {
    rt = (wg >> 3) & 15;
    bh = (wg & 7) + ((wg >> 7) << 3);
}

// ---------------------------------------------------------------------------
// FUSED attention: pass A = stats+PV (lsum, ctx), pass B = attn write with
// in-register iL. Loop bodies are the verified round-12/14 bodies; exp is
// now a bare v_exp_f32 (scores arrive pre-scaled by log2e).
// ---------------------------------------------------------------------------
__global__ __launch_bounds__(256) void k_att(
    const short* __restrict__ qh, const short* __restrict__ ql,
    const short* __restrict__ kh, const short* __restrict__ kl,
    const short* __restrict__ vtb,
    short* __restrict__ ctxb, float* __restrict__ attn)
{
    __shared__ short KsH[4096], KsL[4096], Vs[4096];
    __shared__ short plbf[4][32][72];
    const int tid = threadIdx.x;
    const int w = tid >> 6, lane = tid & 63;
    const int lr = lane & 15, lg = lane >> 4;
    int bh, rt;
    att_decode2(blockIdx.x, bh, rt);
    const int row0 = rt * 128 + w * 16;    // set0 rows; set1 = +64
    const size_t base = (size_t)bh * NS * NDK;
    const short* vb = vtb + (size_t)bh * NDK * NS;
    float* ab = attn + (size_t)bh * NS * NS;
    const int srow0 = tid >> 3, sb8 = tid & 7;
    const int srow1 = srow0 + 32;

    short8 ah[2][2], al[2][2];
#pragma unroll
    for (int st = 0; st < 2; ++st)
#pragma unroll
        for (int ks = 0; ks < 2; ++ks) {
            size_t idx = base + (size_t)(row0 + st * 64 + lr) * NDK + ks * 32 + lg * 8;
            ah[st][ks] = *(const short8*)&qh[idx];
            al[st][ks] = *(const short8*)&ql[idx];
        }

    float lsum[2][4] = {};
    f32x4 vacc[2][4] = {};

    // ================= PASS A: stats + PV =================
    short8 nh0, nh1, nl0, nl1, nv0, nv1;
    {
        nh0 = *(const short8*)&kh[base + (size_t)(srow0) * NDK + sb8 * 8];
        nh1 = *(const short8*)&kh[base + (size_t)(srow1) * NDK + sb8 * 8];
        nl0 = *(const short8*)&kl[base + (size_t)(srow0) * NDK + sb8 * 8];
        nl1 = *(const short8*)&kl[base + (size_t)(srow1) * NDK + sb8 * 8];
        nv0 = *(const short8*)&vb[(size_t)srow0 * NS + sb8 * 8];
        nv1 = *(const short8*)&vb[(size_t)srow1 * NS + sb8 * 8];
    }

    for (int c = 0; c < 32; ++c) {
        short8 ch0 = nh0, ch1 = nh1, cl0 = nl0, cl1 = nl1, cv0 = nv0, cv1 = nv1;
        __syncthreads();
        *(short8*)&KsH[swzS(srow0, sb8)] = ch0;
        *(short8*)&KsH[swzS(srow1, sb8)] = ch1;
        *(short8*)&KsL[swzS(srow0, sb8)] = cl0;
        *(short8*)&KsL[swzS(srow1, sb8)] = cl1;
        *(short8*)&Vs[swzS(srow0, sb8)] = cv0;
        *(short8*)&Vs[swzS(srow1, sb8)] = cv1;
        __syncthreads();

        if (c < 31) {
            const int coln = (c + 1) * 64;
            nh0 = *(const short8*)&kh[base + (size_t)(coln + srow0) * NDK + sb8 * 8];
            nh1 = *(const short8*)&kh[base + (size_t)(coln + srow1) * NDK + sb8 * 8];
            nl0 = *(const short8*)&kl[base + (size_t)(coln + srow0) * NDK + sb8 * 8];
            nl1 = *(const short8*)&kl[base + (size_t)(coln + srow1) * NDK + sb8 * 8];
            nv0 = *(const short8*)&vb[(size_t)srow0 * NS + coln + sb8 * 8];
            nv1 = *(const short8*)&vb[(size_t)srow1 * NS + coln + sb8 * 8];
        }

        f32x4 sa[2][4] = {};
#pragma unroll
        for (int cs = 0; cs < 4; ++cs)
#pragma unroll
            for (int ks = 0; ks < 2; ++ks) {
                short8 fh = *(const short8*)&KsH[swzS(cs * 16 + lr, ks * 4 + lg)];
                short8 fl = *(const short8*)&KsL[swzS(cs * 16 + lr, ks * 4 + lg)];
#pragma unroll
                for (int st = 0; st < 2; ++st) {
                    sa[st][cs] = __builtin_amdgcn_mfma_f32_16x16x32_bf16(ah[st][ks], fh, sa[st][cs], 0, 0, 0);
                    sa[st][cs] = __builtin_amdgcn_mfma_f32_16x16x32_bf16(ah[st][ks], fl, sa[st][cs], 0, 0, 0);
                    sa[st][cs] = __builtin_amdgcn_mfma_f32_16x16x32_bf16(al[st][ks], fh, sa[st][cs], 0, 0, 0);
                }
            }

#pragma unroll
        for (int st = 0; st < 2; ++st)
#pragma unroll
            for (int cs = 0; cs < 4; ++cs)
#pragma unroll
                for (int r = 0; r < 4; ++r) {
                    float e = __builtin_amdgcn_exp2f(fminf(sa[st][cs][r], SCLAMP));
                    lsum[st][r] += e;
                    plbf[w][st * 16 + lg * 4 + r][cs * 16 + lr] = f2bf(e);
                }

#pragma unroll
        for (int k2 = 0; k2 < 2; ++k2) {
            short8 pa0 = *(const short8*)&plbf[w][lr][k2 * 32 + lg * 8];
            short8 pa1 = *(const short8*)&plbf[w][16 + lr][k2 * 32 + lg * 8];
#pragma unroll
            for (int d = 0; d < 4; ++d) {
                short8 vf = *(const short8*)&Vs[swzS(d * 16 + lr, k2 * 4 + lg)];
                vacc[0][d] = __builtin_amdgcn_mfma_f32_16x16x32_bf16(pa0, vf, vacc[0][d], 0, 0, 0);
                vacc[1][d] = __builtin_amdgcn_mfma_f32_16x16x32_bf16(pa1, vf, vacc[1][d], 0, 0, 0);
            }
        }
    }

#pragma unroll
    for (int st = 0; st < 2; ++st)
#pragma unroll
        for (int r = 0; r < 4; ++r)
#pragma unroll
            for (int off = 1; off < 16; off <<= 1)
                lsum[st][r] += __shfl_xor(lsum[st][r], off);

    float iL[2][4];
#pragma unroll
    for (int st = 0; st < 2; ++st)
#pragma unroll
        for (int r = 0; r < 4; ++r) iL[st][r] = 1.0f / lsum[st][r];

    const int b_ = bh >> 3, h_ = bh & 7;
#pragma unroll
    for (int st = 0; st < 2; ++st)
#pragma unroll
        for (int d = 0; d < 4; ++d)
#pragma unroll
            for (int r = 0; r < 4; ++r) {
                int row = row0 + st * 64 + lg * 4 + r;
                ctxb[((size_t)b_ * NS + row) * ND + h_ * NDK + d * 16 + lr] =
                    f2bf(vacc[st][d][r] * iL[st][r]);
            }

    // ================= PASS B: attn write (iL in regs) =================
    {
        nh0 = *(const short8*)&kh[base + (size_t)(srow0) * NDK + sb8 * 8];
        nh1 = *(const short8*)&kh[base + (size_t)(srow1) * NDK + sb8 * 8];
        nl0 = *(const short8*)&kl[base + (size_t)(srow0) * NDK + sb8 * 8];
        nl1 = *(const short8*)&kl[base + (size_t)(srow1) * NDK + sb8 * 8];
    }

    for (int c = 0; c < 32; ++c) {
        short8 ch0 = nh0, ch1 = nh1, cl0 = nl0, cl1 = nl1;
        __syncthreads();
        *(short8*)&KsH[swzS(srow0, sb8)] = ch0;
        *(short8*)&KsH[swzS(srow1, sb8)] = ch1;
        *(short8*)&KsL[swzS(srow0, sb8)] = cl0;
        *(short8*)&KsL[swzS(srow1, sb8)] = cl1;
        __syncthreads();

        if (c < 31) {
            const int coln = (c + 1) * 64;
            nh0 = *(const short8*)&kh[base + (size_t)(coln + srow0) * NDK + sb8 * 8];
            nh1 = *(const short8*)&kh[base + (size_t)(coln + srow1) * NDK + sb8 * 8];
            nl0 = *(const short8*)&kl[base + (size_t)(coln + srow0) * NDK + sb8 * 8];
            nl1 = *(const short8*)&kl[base + (size_t)(coln + srow1) * NDK + sb8 * 8];
        }

        const int col0 = c * 64;
        f32x4 sa[2][4] = {};
#pragma unroll
        for (int cs = 0; cs < 4; ++cs)
#pragma unroll
            for (int ks = 0; ks < 2; ++ks) {
                short8 fh = *(const short8*)&KsH[swzS(cs * 16 + lr, ks * 4 + lg)];
                short8 fl = *(const short8*)&KsL[swzS(cs * 16 + lr, ks * 4 + lg)];
#pragma unroll
                for (int st = 0; st < 2; ++st) {
                    sa[st][cs] = __builtin_amdgcn_mfma_f32_16x16x32_bf16(ah[st][ks], fh, sa[st][cs], 0, 0, 0);
                    sa[st][cs] = __builtin_amdgcn_mfma_f32_16x16x32_bf16(ah[st][ks], fl, sa[st][cs], 0, 0, 0);
                    sa[st][cs] = __builtin_amdgcn_mfma_f32_16x16x32_bf16(al[st][ks], fh, sa[st][cs], 0, 0, 0);
                }
            }

#pragma unroll
        for (int st = 0; st < 2; ++st)
#pragma unroll
            for (int cs = 0; cs < 4; ++cs)
#pragma unroll
                for (int r = 0; r < 4; ++r) {
                    float p = __builtin_amdgcn_exp2f(fminf(sa[st][cs][r], SCLAMP)) * iL[st][r];
                    ab[(size_t)(row0 + st * 64 + lg * 4 + r) * NS + col0 + cs * 16 + lr] = p;
                }
    }
}

// ---------------------------------------------------------------------------
// Out-projection via MFMA: out = ctx_bf16 @ Wo^T + bo + residual (f32 out).
// ---------------------------------------------------------------------------
__global__ __launch_bounds__(256) void k_outproj_m(
    const short* __restrict__ Xc, const float* __restrict__ W,
    const float* __restrict__ bias, const float* __restrict__ Qin,
    float* __restrict__ out)
{
    __shared__ short WsH[8192], WsL[8192];   // [128 rows][64 k] swizzled
    const int tid = threadIdx.x;
    const int w = tid >> 6, lane = tid & 63;
    const int lr = lane & 15, lg = lane >> 4;
    const int row0 = blockIdx.y * 64;
    const int col0 = blockIdx.x * 128;
    const int xrow = row0 + w * 16 + lr;

    f32x4 acc[8] = {};

    float4 wb[8];
    short8 abn[2];
#pragma unroll
    for (int i = 0; i < 8; ++i) {
        int idx = tid + 256 * i, wrow = idx >> 4, g4 = idx & 15;
        wb[i] = *(const float4*)&W[(size_t)(col0 + wrow) * ND + g4 * 4];
    }
#pragma unroll
    for (int ks = 0; ks < 2; ++ks)
        abn[ks] = *(const short8*)&Xc[(size_t)xrow * ND + ks * 32 + lg * 8];

    for (int kc = 0; kc < 8; ++kc) {
        __syncthreads();
#pragma unroll
        for (int i = 0; i < 8; ++i) {
            int idx = tid + 256 * i, wrow = idx >> 4, g4 = idx & 15;
            s16x4 hv, lv;
            unsigned p0 = splitT(wb[i].x), p1 = splitT(wb[i].y);
            unsigned p2 = splitT(wb[i].z), p3 = splitT(wb[i].w);
            hv[0] = (short)p0; lv[0] = (short)(p0 >> 16);
            hv[1] = (short)p1; lv[1] = (short)(p1 >> 16);
            hv[2] = (short)p2; lv[2] = (short)(p2 >> 16);
            hv[3] = (short)p3; lv[3] = (short)(p3 >> 16);
            int off = swz4(wrow, g4);
            *(s16x4*)&WsH[off] = hv;
            *(s16x4*)&WsL[off] = lv;
        }
        __syncthreads();

        short8 ah[2] = { abn[0], abn[1] };

        if (kc < 7) {
            const int kn = (kc + 1) * 64;
#pragma unroll
            for (int i = 0; i < 8; ++i) {
                int idx = tid + 256 * i, wrow = idx >> 4, g4 = idx & 15;
                wb[i] = *(const float4*)&W[(size_t)(col0 + wrow) * ND + kn + g4 * 4];
            }
#pragma unroll
            for (int ks = 0; ks < 2; ++ks)
                abn[ks] = *(const short8*)&Xc[(size_t)xrow * ND + kn + ks * 32 + lg * 8];
        }

#pragma unroll
        for (int cs = 0; cs < 8; ++cs)
#pragma unroll
            for (int ks = 0; ks < 2; ++ks) {
                short8 fh = *(const short8*)&WsH[swzS(cs * 16 + lr, ks * 4 + lg)];
                short8 fl = *(const short8*)&WsL[swzS(cs * 16 + lr, ks * 4 + lg)];
                acc[cs] = __builtin_amdgcn_mfma_f32_16x16x32_bf16(ah[ks], fh, acc[cs], 0, 0, 0);
                acc[cs] = __builtin_amdgcn_mfma_f32_16x16x32_bf16(ah[ks], fl, acc[cs], 0, 0, 0);
            }
    }

#pragma unroll
    for (int cs = 0; cs < 8; ++cs) {
        int c = col0 + cs * 16 + lr;
        float bv = bias[c];
#pragma unroll
        for (int r = 0; r < 4; ++r) {
            int gr = row0 + w * 16 + lg * 4 + r;
            float res = Qin[(size_t)gr * ND + c];
            out[(size_t)gr * ND + c] = acc[cs][r] + bv + res;
        }
    }
}

// ---------------------------------------------------------------------------
// In-place LayerNorm over last dim (512).
// ---------------------------------------------------------------------------
__global__ __launch_bounds__(256) void k_ln(
    float* __restrict__ out, const float* __restrict__ gamma,
    const float* __restrict__ beta)
{
    const int tid = threadIdx.x;
    float* p = out + (size_t)blockIdx.x * ND;
    float2 v = *(const float2*)&p[tid * 2];

    float s = v.x + v.y;
#pragma unroll
    for (int off = 32; off > 0; off >>= 1) s += __shfl_xor(s, off);
    __shared__ float red1[4];
    __shared__ float red2[4];
    if ((tid & 63) == 0) red1[tid >> 6] = s;
    __syncthreads();
    const float mu = (red1[0] + red1[1] + red1[2] + red1[3]) * (1.0f / ND);

    float dx = v.x - mu, dy = v.y - mu;
    float q = dx * dx + dy * dy;
#pragma unroll
    for (int off = 32; off > 0; off >>= 1) q += __shfl_xor(q, off);
    if ((tid & 63) == 0) red2[tid >> 6] = q;
    __syncthreads();
    const float var = (red2[0] + red2[1] + red2[2] + red2[3]) * (1.0f / ND);
    const float inv = rsqrtf(var + LN_EPS);

    float2 g = *(const float2*)&gamma[tid * 2];
    float2 be = *(const float2*)&beta[tid * 2];
    float2 o = { dx * inv * g.x + be.x, dy * inv * g.y + be.y };
    *(float2*)&p[tid * 2] = o;
}

// ---------------------------------------------------------------------------
extern "C" void kernel_launch(void* const* d_in, const int* in_sizes, int n_in,
                              void* d_out, int out_size, void* d_ws, size_t ws_size,
                              hipStream_t stream)
{
    const float* Q    = (const float*)d_in[0];
    const float* K    = (const float*)d_in[1];
    const float* V    = (const float*)d_in[2];
    const float* Wq   = (const float*)d_in[3];
    const float* bq   = (const float*)d_in[4];
    const float* Wk   = (const float*)d_in[5];
    const float* bk   = (const float*)d_in[6];
    const float* Wv   = (const float*)d_in[7];
    const float* bv   = (const float*)d_in[8];
    const float* Wo   = (const float*)d_in[9];
    const float* bo   = (const float*)d_in[10];
    const float* gam  = (const float*)d_in[11];
    const float* bet  = (const float*)d_in[12];

    float* out  = (float*)d_out;                       // [NB*NS*ND]
    float* attn = out + (size_t)NB * NS * ND;          // [NB*NH*NS*NS]

    const size_t QKV = (size_t)NB * NH * NS * NDK;     // 4.19M elements
    short* qh   = (short*)d_ws;
    short* ql   = qh + QKV;
    short* kh   = ql + QKV;
    short* kl   = kh + QKV;
    short* vtb  = kl + QKV;
    short* ctxb = vtb + QKV;

    dim3 blk(256);

    dim3 gP(ND / 128, (NB * NS) / 64, 3);              // (4, 128, 3)
    k_projm_all<<<gP, blk, 0, stream>>>(Q, K, V, Wq, bq, Wk, bk, Wv, bv,
                                        qh, ql, kh, kl, vtb);

    dim3 gAtt((NS / 128) * NB * NH);                   // 512, XCD-remapped
    k_att<<<gAtt, blk, 0, stream>>>(qh, ql, kh, kl, vtb, ctxb, attn);

    dim3 gO(ND / 128, (NB * NS) / 64);                 // (4, 128)
    k_outproj_m<<<gO, blk, 0, stream>>>(ctxb, Wo, bo, Q, out);

    k_ln<<<dim3(NB * NS), blk, 0, stream>>>(out, gam, bet);
}